// Round 8
// baseline (4967.921 us; speedup 1.0000x reference)
//
#include <hip/hip_runtime.h>

// LSTM T=16384, B=32, H=96. 32 blocks (1/batch). History: R18 6-wave MFMA-cols
// = 5142us; R20 8-wave (18 MFMA/SIMD balanced) = 4586us, prediction matched.
// Conceptual note: dual-domain batch-packing (R16/R19) can NEVER help -- 224
// CUs idle, wall-clock = per-step LATENCY x T; other batches fill stalls but
// don't shorten the serial chain. Step budget @2.4GHz: 672cy = 290 burst
// (18 MFMA/SIMD, floor: vector x matrix caps useful MACs at 512/MFMA -> 72/CU)
// + ~120 ds_read + ~80 tail + ~60 write/barrier + ~120 SLOP.
// R21 (this): attack the slop, keep the verified structure.
//   - 12 waves x 8 cells (2 tiles x 3 kt = 6 MFMA/wave): same 18 MFMA/SIMD
//     burst, but 3 waves/SIMD smooth pipe gaps + arrival jitter; tail tile
//     select 2 cndmask -> 1; Bw 36 -> 24 VGPRs; h16>=2 lanes mirror te=h16&1.
//   - 8-step unroll: pointer advances halved, ds offsets immediate.
//   - C-init: 2 acc tiles (8 regs) not 3 (12).
// Unchanged (HW-verified): A = h replicated rows (3x ds_read_b128 per lane,
// k-slice 8*h16), B = weights cols (tile t col c -> cell 4t+(c>>2), gate c&3),
// gx seeded in C reg0, quad DPP tail, e_k prefold, scaled-domain c,
// 513-row slot-shifted history, one barrier/step, bulk fc flush per window.

constexpr int HH   = 96;
constexpr int BB   = 32;
constexpr int TT   = 16384;
constexpr int TH   = 768;   // 12 waves, 3 per SIMD
constexpr int NS   = 512;   // h history window
constexpr int ROWP = 104;   // halves per hist row: 208 B, 16B-aligned

typedef _Float16 f16x8 __attribute__((ext_vector_type(8)));
typedef _Float16 f16x2 __attribute__((ext_vector_type(2)));
typedef float    f32x4 __attribute__((ext_vector_type(4)));

template <int CTRL>
__device__ __forceinline__ float dpp_bcast(float v) {
    int r = __builtin_amdgcn_mov_dpp(__builtin_bit_cast(int, v), CTRL, 0xF, 0xF, true);
    return __builtin_bit_cast(float, r);
}
constexpr int DPP_B1 = 0x55;
constexpr int DPP_B2 = 0xAA;
constexpr int DPP_B3 = 0xFF;

#define LOG2E 1.44269504f

__attribute__((amdgpu_flat_work_group_size(TH, TH)))
__global__ void lstm_kernel(const float* __restrict__ x,
                            const float* __restrict__ w_ih,
                            const float* __restrict__ w_hh,
                            const float* __restrict__ b_ih,
                            const float* __restrict__ b_hh,
                            const float* __restrict__ fc_w,
                            const float* __restrict__ fc_b,
                            float* __restrict__ out) {
    __shared__ __align__(16) _Float16 hist[(NS + 1) * ROWP];  // ~104 KB
    __shared__ __align__(16) float xs[NS];                    // 2 KB x window
    __shared__ float fcw_s[HH];

    const int tid = threadIdx.x;
    const int b   = blockIdx.x;
    const int wv  = tid >> 6;   // wave 0..11, owns cells [8wv, 8wv+8)
    const int l   = tid & 63;
    const int h16 = l >> 4;     // k-group 0..3; tail tile = h16&1
    const int rIn = l & 15;     // col within tile
    const int s   = rIn & 3;    // gate 0..3 (quad lane)
    const int q   = rIn >> 2;   // cell-sub within tile
    const int te  = h16 & 1;    // tail tile (h16>=2 mirrors h16-2)
    const int j   = 8 * wv + 4 * te + q;     // this lane's cell 0..95

    // B fragments (weights), e_k-prescaled. Tile t col rIn holds W row
    // (gate s, cell 8wv+4t+q); lane's k slice = kt*32 + 8*h16 + e.
    const float ek_s = (s == 2) ? (-2.0f * LOG2E) : (-LOG2E);
    f16x8 Bw[2][3];
#pragma unroll
    for (int t = 0; t < 2; ++t) {
        const float* wrow = w_hh + (s * HH + 8 * wv + 4 * t + q) * HH;
#pragma unroll
        for (int kt = 0; kt < 3; ++kt) {
            const float* wr = wrow + kt * 32 + 8 * h16;
            f16x8 v;
#pragma unroll
            for (int e = 0; e < 8; ++e) v[e] = (_Float16)(wr[e] * ek_s);
            Bw[t][kt] = v;
        }
    }
#pragma unroll
    for (int t = 0; t < 2; ++t)
#pragma unroll
        for (int kt = 0; kt < 3; ++kt) asm volatile("" : "+v"(Bw[t][kt]));

    const float wih2  = w_ih[s * HH + j] * ek_s;
    const float bias2 = (b_ih[s * HH + j] + b_hh[s * HH + j]) * ek_s;
    const float a_mul = (s == 2) ? (-4.0f * LOG2E) : 1.0f;
    const float a_add = (s == 2) ? (2.0f * LOG2E) : 0.0f;
    const bool  te1 = (te == 1);

    const float fcb = fc_b[0];
    float c = 0.0f;   // scaled domain: c' = -2*log2e * c_true

    for (int i = tid; i < HH; i += TH) fcw_s[i] = fc_w[i];

    // Bulk fc projection for window [t0, t0+NS): h(t0+i) is in hist row i+1.
    auto flush = [&](int t0) {
        for (int i = tid; i < NS; i += TH) {
            const uint2* hr = (const uint2*)(hist + (i + 1) * ROWP);
            float a = 0.0f;
#pragma unroll
            for (int m = 0; m < 24; ++m) {
                uint2 u = hr[m];
                f16x2 p0 = __builtin_bit_cast(f16x2, u.x);
                f16x2 p1 = __builtin_bit_cast(f16x2, u.y);
                a = fmaf((float)p0.x, fcw_s[4 * m + 0], a);
                a = fmaf((float)p0.y, fcw_s[4 * m + 1], a);
                a = fmaf((float)p1.x, fcw_s[4 * m + 2], a);
                a = fmaf((float)p1.y, fcw_s[4 * m + 3], a);
            }
            out[(t0 + i) * BB + b] = a + fcb + xs[i];
        }
    };

    const _Float16* rd_p;  // h(t-1) k-slice base (8*h16); +8 rows per block
    _Float16*       wr_p;  // h(t) cell slot base

    auto step = [&](float gx, const int ofs) {   // ofs: constant element offset
        const uint4* p = (const uint4*)(rd_p + ofs);
        uint4 u0 = p[0], u1 = p[4], u2 = p[8];   // kt stride: 32 halves = 64B
        const f16x8 a0 = __builtin_bit_cast(f16x8, u0);
        const f16x8 a1 = __builtin_bit_cast(f16x8, u1);
        const f16x8 a2 = __builtin_bit_cast(f16x8, u2);

        // C-init carries gx: lane (h16,rIn) seeds elem (row 4h16, col rIn)
        // of both tiles and reads back exactly its own seed from tile te.
        const f32x4 cz = {gx, 0.f, 0.f, 0.f};
        f32x4 acc[2] = {cz, cz};
        // kt-outer: 2 tile-chains interleave; C-forwarding runs at full rate.
#pragma unroll
        for (int t = 0; t < 2; ++t)
            acc[t] = __builtin_amdgcn_mfma_f32_16x16x32_f16(a0, Bw[t][0], acc[t], 0, 0, 0);
#pragma unroll
        for (int t = 0; t < 2; ++t)
            acc[t] = __builtin_amdgcn_mfma_f32_16x16x32_f16(a1, Bw[t][1], acc[t], 0, 0, 0);
#pragma unroll
        for (int t = 0; t < 2; ++t)
            acc[t] = __builtin_amdgcn_mfma_f32_16x16x32_f16(a2, Bw[t][2], acc[t], 0, 0, 0);

        // Rows are replicas -> reg 0 always; 1 cndmask tile select by te.
        const float pre = te1 ? acc[1][0] : acc[0][0];

        const float act =
            fmaf(__builtin_amdgcn_rcpf(1.0f + __builtin_amdgcn_exp2f(pre)),
                 a_mul, a_add);
        const float fv = dpp_bcast<DPP_B1>(act);
        const float gv = dpp_bcast<DPP_B2>(act);   // already -2k-scaled
        const float ov = dpp_bcast<DPP_B3>(act);
        c = fmaf(fv, c, act * gv);                 // scaled domain
        const float rt = __builtin_amdgcn_rcpf(1.0f + __builtin_amdgcn_exp2f(c));
        const float h  = fmaf(ov + ov, rt, -ov);   // o * tanh(c_true)
        if (s == 0 && h16 < 2) *(wr_p + ofs) = (_Float16)h;
        __syncthreads();
    };

    for (int w = 0; w < TT / NS; ++w) {
        const int t0 = w * NS;
        if (w == 0) {
            if (tid < 48) ((uint32_t*)hist)[tid] = 0u;  // row 0 = h(-1) = 0
        } else {
            flush(t0 - NS);                              // old xs + rows 1..512
            if (tid < 48)                                // row 512 -> row 0
                ((uint32_t*)hist)[tid] = ((const uint32_t*)(hist + NS * ROWP))[tid];
        }
        __syncthreads();
        for (int i = tid; i < NS; i += TH) xs[i] = x[(t0 + i) * BB + b];
        __syncthreads();

        rd_p = hist + 8 * h16;
        wr_p = hist + ROWP + j;
        for (int tt = 0; tt < NS; tt += 8) {
            const float4 xq0 = *(const float4*)(xs + tt);      // broadcast
            const float4 xq1 = *(const float4*)(xs + tt + 4);
            const float g0 = fmaf(xq0.x, wih2, bias2);         // off-chain
            const float g1 = fmaf(xq0.y, wih2, bias2);
            const float g2 = fmaf(xq0.z, wih2, bias2);
            const float g3 = fmaf(xq0.w, wih2, bias2);
            const float g4 = fmaf(xq1.x, wih2, bias2);
            const float g5 = fmaf(xq1.y, wih2, bias2);
            const float g6 = fmaf(xq1.z, wih2, bias2);
            const float g7 = fmaf(xq1.w, wih2, bias2);
            step(g0, 0 * ROWP);
            step(g1, 1 * ROWP);
            step(g2, 2 * ROWP);
            step(g3, 3 * ROWP);
            step(g4, 4 * ROWP);
            step(g5, 5 * ROWP);
            step(g6, 6 * ROWP);
            step(g7, 7 * ROWP);
            rd_p += 8 * ROWP;
            wr_p += 8 * ROWP;
        }
    }
    flush(TT - NS);   // last window (loop ended with a barrier)
}

extern "C" void kernel_launch(void* const* d_in, const int* in_sizes, int n_in,
                              void* d_out, int out_size, void* d_ws, size_t ws_size,
                              hipStream_t stream) {
    const float* x    = (const float*)d_in[0];
    const float* w_ih = (const float*)d_in[1];
    const float* w_hh = (const float*)d_in[2];
    const float* b_ih = (const float*)d_in[3];
    const float* b_hh = (const float*)d_in[4];
    const float* fc_w = (const float*)d_in[5];
    const float* fc_b = (const float*)d_in[6];
    float* out = (float*)d_out;

    lstm_kernel<<<dim3(BB), dim3(TH), 0, stream>>>(x, w_ih, w_hh, b_ih, b_hh,
                                                   fc_w, fc_b, out);
}